// Round 1
// baseline (7777.025 us; speedup 1.0000x reference)
//
#include <hip/hip_runtime.h>
#include <math.h>

#define Bb 2
#define Ss 2048
#define Cc 1536
#define HQ 8
#define DQK 128
#define DV 192
#define ROWS (Bb*Ss)          // 4096
#define EPSf 1e-5f
#define CLIPf 5.0f
#define QROWS 4

// ---------------- reduction helpers ----------------
__device__ __forceinline__ float wave_sum(float v) {
#pragma unroll
    for (int off = 32; off >= 1; off >>= 1) v += __shfl_xor(v, off);
    return v;
}
__device__ __forceinline__ float wave_max(float v) {
#pragma unroll
    for (int off = 32; off >= 1; off >>= 1) v = fmaxf(v, __shfl_xor(v, off));
    return v;
}
__device__ __forceinline__ float blk_sum(float v, float* sm) {
    v = wave_sum(v);
    int wid = threadIdx.x >> 6, lane = threadIdx.x & 63;
    int nw = blockDim.x >> 6;
    if (lane == 0) sm[wid] = v;
    __syncthreads();
    float r = sm[0];
    for (int i = 1; i < nw; ++i) r += sm[i];
    __syncthreads();
    return r;
}
__device__ __forceinline__ float blk_max(float v, float* sm) {
    v = wave_max(v);
    int wid = threadIdx.x >> 6, lane = threadIdx.x & 63;
    int nw = blockDim.x >> 6;
    if (lane == 0) sm[wid] = v;
    __syncthreads();
    float r = sm[0];
    for (int i = 1; i < nw; ++i) r = fmaxf(r, sm[i]);
    __syncthreads();
    return r;
}

// ---------------- rms_bn (per-channel over B*S) ----------------
__global__ void sq_reduce(const float* __restrict__ x, float* __restrict__ ms, int ncols) {
    int ch = blockIdx.x * blockDim.x + threadIdx.x;
    int r0 = blockIdx.y * 128;
    float acc = 0.f;
    for (int r = r0; r < r0 + 128; ++r) {
        float v = x[(size_t)r * ncols + ch];
        acc += v * v;
    }
    atomicAdd(&ms[ch], acc);
}

__global__ void rms_apply(const float* __restrict__ x, const float* __restrict__ ms,
                          const float* __restrict__ scale, float* __restrict__ out,
                          int ncols, size_t total) {
    for (size_t i = (size_t)blockIdx.x * blockDim.x + threadIdx.x; i < total;
         i += (size_t)gridDim.x * blockDim.x) {
        int ch = (int)(i % ncols);
        out[i] = x[i] * rsqrtf(ms[ch] * (1.0f / (float)ROWS) + EPSf) * scale[ch];
    }
}

// ---------------- fp32 GEMM: C[M,N] = A[M,K] * W[N,K]^T (+ bias) ----------------
// 64x64 tile, 256 threads, 4x4 per thread, K-tile 16. M,N % 64 == 0, K % 16 == 0.
__global__ __launch_bounds__(256) void gemm_abT(const float* __restrict__ A,
                                                const float* __restrict__ W,
                                                const float* __restrict__ bias,
                                                float* __restrict__ Cout,
                                                int M, int N, int K, int hasBias) {
    __shared__ float As[16][65];
    __shared__ float Ws[16][65];
    int tid = threadIdx.x;
    int m0 = blockIdx.y * 64, n0 = blockIdx.x * 64;
    int ty = tid >> 4, tx = tid & 15;
    float acc[4][4] = {};
    for (int k0 = 0; k0 < K; k0 += 16) {
#pragma unroll
        for (int i = 0; i < 4; ++i) {
            int idx = tid + i * 256;
            int r = idx >> 4, kk = idx & 15;
            As[kk][r] = A[(size_t)(m0 + r) * K + k0 + kk];
            Ws[kk][r] = W[(size_t)(n0 + r) * K + k0 + kk];
        }
        __syncthreads();
#pragma unroll
        for (int kk = 0; kk < 16; ++kk) {
            float a[4], w[4];
#pragma unroll
            for (int i = 0; i < 4; ++i) a[i] = As[kk][ty * 4 + i];
#pragma unroll
            for (int j = 0; j < 4; ++j) w[j] = Ws[kk][tx * 4 + j];
#pragma unroll
            for (int i = 0; i < 4; ++i)
#pragma unroll
                for (int j = 0; j < 4; ++j) acc[i][j] += a[i] * w[j];
        }
        __syncthreads();
    }
#pragma unroll
    for (int i = 0; i < 4; ++i)
#pragma unroll
        for (int j = 0; j < 4; ++j) {
            float bv = hasBias ? bias[n0 + tx * 4 + j] : 0.f;
            Cout[(size_t)(m0 + ty * 4 + i) * N + n0 + tx * 4 + j] = acc[i][j] + bv;
        }
}

// ---------------- LayerNorm (+ optional RoPE), in-place, one block per row ----------------
template <int D, int ROPE>
__global__ void ln_rope(float* __restrict__ data, const float* __restrict__ w,
                        const float* __restrict__ b, int gdiv) {
    __shared__ float sm[8];
    __shared__ float buf[D];
    int row = blockIdx.x;
    int tid = threadIdx.x;
    float val = data[(size_t)row * D + tid];
    float mu = blk_sum(val, sm) * (1.0f / D);
    float dv = val - mu;
    float var = blk_sum(dv * dv, sm) * (1.0f / D);
    float normed = dv * rsqrtf(var + EPSf) * w[tid] + b[tid];
    if (ROPE) {
        int s = (row / gdiv) % Ss;
        buf[tid] = normed;
        __syncthreads();
        int i = tid >> 1;
        // geom = exp(i * log(MAX_POS - nf + 1)/ (nf-1)), nf = 64, MAX_POS=8192 -> log(8129)
        float geom = expf((float)i * (logf(8129.0f) / 63.0f));
        float invf = 1.0f / ((float)i + geom);
        float theta = (float)s * invf;
        float cth = cosf(theta), sth = sinf(theta);
        float other = buf[tid ^ 1];
        float res = ((tid & 1) == 0) ? (normed * cth - other * sth)
                                     : (normed * cth + other * sth);
        data[(size_t)row * D + tid] = res;
    } else {
        data[(size_t)row * D + tid] = normed;
    }
}

// ---------------- attention: one block per (b, g, 4 query rows) ----------------
__global__ __launch_bounds__(256) void attn_kernel(const float* __restrict__ q,
                                                   const float* __restrict__ k,
                                                   const float* __restrict__ v,
                                                   float* __restrict__ y) {
    int b = blockIdx.z, g = blockIdx.y, s0 = blockIdx.x * QROWS;
    __shared__ float qs[QROWS][DQK];
    __shared__ float p[QROWS][Ss];     // 32 KB
    __shared__ float sred[4];
    int tid = threadIdx.x;

    for (int idx = tid; idx < QROWS * DQK; idx += 256) {
        int r = idx / DQK, d = idx % DQK;
        qs[r][d] = q[(size_t)((b * Ss + s0 + r) * HQ + g) * DQK + d];
    }
    __syncthreads();

    const float scale = 0.088388347648318447f;  // 1/sqrt(128)
    for (int t = tid; t < Ss; t += 256) {
        const float* krow = &k[(size_t)(b * Ss + t) * DQK];
        float acc[QROWS] = {0.f, 0.f, 0.f, 0.f};
        for (int d = 0; d < DQK; d += 4) {
            float4 kv = *(const float4*)&krow[d];
#pragma unroll
            for (int r = 0; r < QROWS; ++r) {
                acc[r] += qs[r][d] * kv.x + qs[r][d + 1] * kv.y +
                          qs[r][d + 2] * kv.z + qs[r][d + 3] * kv.w;
            }
        }
#pragma unroll
        for (int r = 0; r < QROWS; ++r)
            p[r][t] = CLIPf * tanhf(acc[r] * scale * (1.0f / CLIPf));
    }
    __syncthreads();

    float inv_sum[QROWS];
    for (int r = 0; r < QROWS; ++r) {
        float m = -1e30f;
        for (int t = tid; t < Ss; t += 256) m = fmaxf(m, p[r][t]);
        m = blk_max(m, sred);
        float sum = 0.f;
        for (int t = tid; t < Ss; t += 256) {
            float e = expf(p[r][t] - m);
            p[r][t] = e;
            sum += e;
        }
        sum = blk_sum(sum, sred);
        inv_sum[r] = 1.0f / sum;
    }
    __syncthreads();

    for (int d = tid; d < DV; d += 256) {
        float acc[QROWS] = {0.f, 0.f, 0.f, 0.f};
        for (int t = 0; t < Ss; ++t) {
            float vv = v[(size_t)(b * Ss + t) * DV + d];
#pragma unroll
            for (int r = 0; r < QROWS; ++r) acc[r] += p[r][t] * vv;
        }
#pragma unroll
        for (int r = 0; r < QROWS; ++r)
            y[(size_t)(b * Ss + s0 + r) * (HQ * DV) + g * DV + d] = acc[r] * inv_sum[r];
    }
}

// ---------------- launch ----------------
extern "C" void kernel_launch(void* const* d_in, const int* in_sizes, int n_in,
                              void* d_out, int out_size, void* d_ws, size_t ws_size,
                              hipStream_t stream) {
    const float* x         = (const float*)d_in[0];
    const float* bn1_scale = (const float*)d_in[1];
    const float* q_w       = (const float*)d_in[2];
    const float* k_w       = (const float*)d_in[3];
    const float* v_w       = (const float*)d_in[4];
    const float* qn_w      = (const float*)d_in[5];
    const float* qn_b      = (const float*)d_in[6];
    const float* kn_w      = (const float*)d_in[7];
    const float* kn_b      = (const float*)d_in[8];
    const float* vn_w      = (const float*)d_in[9];
    const float* vn_b      = (const float*)d_in[10];
    const float* bn2_scale = (const float*)d_in[11];
    const float* out_w     = (const float*)d_in[12];
    const float* out_b     = (const float*)d_in[13];
    float* out = (float*)d_out;

    float* ws   = (float*)d_ws;
    float* ms1  = ws;                       // 1536
    float* ms2  = ws + 1536;                // 1536
    float* xb   = ws + 4096;                // 4096*1536
    float* qb   = xb + (size_t)ROWS * Cc;   // 4096*1024
    float* kb   = qb + (size_t)ROWS * HQ * DQK;  // 4096*128
    float* vb   = kb + (size_t)ROWS * DQK;       // 4096*192
    float* ya   = vb + (size_t)ROWS * DV;        // 4096*1536
    float* proj = xb;  // xb dead after QKV GEMMs

    hipMemsetAsync(ms1, 0, 2 * Cc * sizeof(float), stream);

    // rms_bn1
    sq_reduce<<<dim3(Cc / 256, ROWS / 128), 256, 0, stream>>>(x, ms1, Cc);
    rms_apply<<<2048, 256, 0, stream>>>(x, ms1, bn1_scale, xb, Cc, (size_t)ROWS * Cc);

    // QKV projections
    gemm_abT<<<dim3((HQ * DQK) / 64, ROWS / 64), 256, 0, stream>>>(
        xb, q_w, nullptr, qb, ROWS, HQ * DQK, Cc, 0);
    gemm_abT<<<dim3(DQK / 64, ROWS / 64), 256, 0, stream>>>(
        xb, k_w, nullptr, kb, ROWS, DQK, Cc, 0);
    gemm_abT<<<dim3(DV / 64, ROWS / 64), 256, 0, stream>>>(
        xb, v_w, nullptr, vb, ROWS, DV, Cc, 0);

    // LayerNorm + RoPE
    ln_rope<DQK, 1><<<ROWS * HQ, DQK, 0, stream>>>(qb, qn_w, qn_b, HQ);
    ln_rope<DQK, 1><<<ROWS, DQK, 0, stream>>>(kb, kn_w, kn_b, 1);
    ln_rope<DV, 0><<<ROWS, DV, 0, stream>>>(vb, vn_w, vn_b, 1);

    // attention
    attn_kernel<<<dim3(Ss / QROWS, HQ, Bb), 256, 0, stream>>>(qb, kb, vb, ya);

    // output projection + bias
    gemm_abT<<<dim3(Cc / 64, ROWS / 64), 256, 0, stream>>>(
        ya, out_w, out_b, proj, ROWS, Cc, Cc, 1);

    // rms_bn2
    sq_reduce<<<dim3(Cc / 256, ROWS / 128), 256, 0, stream>>>(proj, ms2, Cc);
    rms_apply<<<2048, 256, 0, stream>>>(proj, ms2, bn2_scale, out, Cc, (size_t)ROWS * Cc);
}

// Round 2
// 1210.964 us; speedup vs baseline: 6.4222x; 6.4222x over previous
//
#include <hip/hip_runtime.h>
#include <hip/hip_bf16.h>
#include <math.h>

#define Bb 2
#define Ss 2048
#define Cc 1536
#define HQ 8
#define DQK 128
#define DV 192
#define ROWS (Bb*Ss)          // 4096
#define EPSf 1e-5f
#define CLIPf 5.0f

typedef short short8 __attribute__((ext_vector_type(8)));
typedef float f32x4 __attribute__((ext_vector_type(4)));
typedef unsigned short ushort;

// ---------------- reduction helpers ----------------
__device__ __forceinline__ float wave_sum(float v) {
#pragma unroll
    for (int off = 32; off >= 1; off >>= 1) v += __shfl_xor(v, off);
    return v;
}
__device__ __forceinline__ float blk_sum(float v, float* sm) {
    v = wave_sum(v);
    int wid = threadIdx.x >> 6, lane = threadIdx.x & 63;
    int nw = blockDim.x >> 6;
    if (lane == 0) sm[wid] = v;
    __syncthreads();
    float r = sm[0];
    for (int i = 1; i < nw; ++i) r += sm[i];
    __syncthreads();
    return r;
}

// ---------------- rms_bn (per-channel over B*S) ----------------
__global__ void sq_reduce(const float* __restrict__ x, float* __restrict__ ms, int ncols) {
    int ch = blockIdx.x * blockDim.x + threadIdx.x;
    int r0 = blockIdx.y * 128;
    float acc = 0.f;
    for (int r = r0; r < r0 + 128; ++r) {
        float v = x[(size_t)r * ncols + ch];
        acc += v * v;
    }
    atomicAdd(&ms[ch], acc);
}

__global__ void rms_apply(const float* __restrict__ x, const float* __restrict__ ms,
                          const float* __restrict__ scale, float* __restrict__ out,
                          int ncols, size_t total) {
    for (size_t i = (size_t)blockIdx.x * blockDim.x + threadIdx.x; i < total;
         i += (size_t)gridDim.x * blockDim.x) {
        int ch = (int)(i % ncols);
        out[i] = x[i] * rsqrtf(ms[ch] * (1.0f / (float)ROWS) + EPSf) * scale[ch];
    }
}

// ---------------- fp32 GEMM: C[M,N] = A[M,K] * W[N,K]^T (+ bias) ----------------
__global__ __launch_bounds__(256) void gemm_abT(const float* __restrict__ A,
                                                const float* __restrict__ W,
                                                const float* __restrict__ bias,
                                                float* __restrict__ Cout,
                                                int M, int N, int K, int hasBias) {
    __shared__ float As[16][65];
    __shared__ float Ws[16][65];
    int tid = threadIdx.x;
    int m0 = blockIdx.y * 64, n0 = blockIdx.x * 64;
    int ty = tid >> 4, tx = tid & 15;
    float acc[4][4] = {};
    for (int k0 = 0; k0 < K; k0 += 16) {
#pragma unroll
        for (int i = 0; i < 4; ++i) {
            int idx = tid + i * 256;
            int r = idx >> 4, kk = idx & 15;
            As[kk][r] = A[(size_t)(m0 + r) * K + k0 + kk];
            Ws[kk][r] = W[(size_t)(n0 + r) * K + k0 + kk];
        }
        __syncthreads();
#pragma unroll
        for (int kk = 0; kk < 16; ++kk) {
            float a[4], w[4];
#pragma unroll
            for (int i = 0; i < 4; ++i) a[i] = As[kk][ty * 4 + i];
#pragma unroll
            for (int j = 0; j < 4; ++j) w[j] = Ws[kk][tx * 4 + j];
#pragma unroll
            for (int i = 0; i < 4; ++i)
#pragma unroll
                for (int j = 0; j < 4; ++j) acc[i][j] += a[i] * w[j];
        }
        __syncthreads();
    }
#pragma unroll
    for (int i = 0; i < 4; ++i)
#pragma unroll
        for (int j = 0; j < 4; ++j) {
            float bv = hasBias ? bias[n0 + tx * 4 + j] : 0.f;
            Cout[(size_t)(m0 + ty * 4 + i) * N + n0 + tx * 4 + j] = acc[i][j] + bv;
        }
}

// ---------------- LayerNorm (+ optional RoPE) -> bf16 out ----------------
template <int D, int ROPE>
__global__ void ln_rope(const float* __restrict__ in, ushort* __restrict__ outb,
                        const float* __restrict__ w, const float* __restrict__ b, int gdiv) {
    __shared__ float sm[8];
    __shared__ float buf[D];
    int row = blockIdx.x;
    int tid = threadIdx.x;
    float val = in[(size_t)row * D + tid];
    float mu = blk_sum(val, sm) * (1.0f / D);
    float dv = val - mu;
    float var = blk_sum(dv * dv, sm) * (1.0f / D);
    float normed = dv * rsqrtf(var + EPSf) * w[tid] + b[tid];
    float res = normed;
    if (ROPE) {
        int s = (row / gdiv) % Ss;
        buf[tid] = normed;
        __syncthreads();
        int i = tid >> 1;
        float geom = expf((float)i * (logf(8129.0f) / 63.0f));
        float invf = 1.0f / ((float)i + geom);
        float theta = (float)s * invf;
        float cth = cosf(theta), sth = sinf(theta);
        float other = buf[tid ^ 1];
        res = ((tid & 1) == 0) ? (normed * cth - other * sth)
                               : (normed * cth + other * sth);
    }
    __hip_bfloat16 hb = __float2bfloat16(res);
    outb[(size_t)row * D + tid] = *reinterpret_cast<ushort*>(&hb);
}

// ---------------- V transpose: vbh[b][t][d] -> vT[b][d][t] (bf16) ----------------
__global__ __launch_bounds__(256) void transpose_v(const ushort* __restrict__ vbh,
                                                   ushort* __restrict__ vT) {
    __shared__ ushort tb[64][72];
    int t0 = blockIdx.x * 64, d0 = blockIdx.y * 64, b = blockIdx.z;
    int tid = threadIdx.x;
#pragma unroll
    for (int i = 0; i < 2; ++i) {
        int ci = tid + i * 256;
        int t = ci >> 3, dc = ci & 7;
        short8 v = *(const short8*)&vbh[((size_t)(b * Ss + t0 + t)) * DV + d0 + dc * 8];
        *(short8*)&tb[t][dc * 8] = v;
    }
    __syncthreads();
#pragma unroll
    for (int i = 0; i < 2; ++i) {
        int ci = tid + i * 256;
        int d = ci >> 3, tc = ci & 7;
        short8 v;
#pragma unroll
        for (int j = 0; j < 8; ++j) v[j] = (short)tb[tc * 8 + j][d];
        *(short8*)&vT[((size_t)(b * DV + d0 + d)) * Ss + t0 + tc * 8] = v;
    }
}

// ---------------- MFMA flash attention ----------------
// grid (S/64, HQ, B), 256 threads (4 waves x 16 q-rows). KV tiles of 64.
__global__ __launch_bounds__(256, 2) void attn_mfma(const ushort* __restrict__ qbh,
                                                    const ushort* __restrict__ kbh,
                                                    const ushort* __restrict__ vT,
                                                    float* __restrict__ ya) {
    __shared__ ushort Klds[64 * 128];    // 16 KB, XOR-swizzled
    __shared__ ushort VTlds[192 * 64];   // 24 KB, XOR-swizzled
    __shared__ ushort Plds[4 * 16 * 64]; // 8 KB, per-wave, XOR-swizzled
    int tid = threadIdx.x;
    int b = blockIdx.z, gq = blockIdx.y;
    int q0 = blockIdx.x * 64;
    int w = tid >> 6, lane = tid & 63;
    int g = lane >> 4, li = lane & 15;
    int mask = (li & 7) << 4;

    // Q fragments held in registers for the whole kernel
    short8 qf[4];
    {
        int qrow = q0 + w * 16 + li;
        const ushort* qptr = qbh + ((size_t)(b * Ss + qrow) * HQ + gq) * DQK + g * 8;
#pragma unroll
        for (int c = 0; c < 4; ++c) qf[c] = *(const short8*)(qptr + c * 32);
    }

    f32x4 pv[12];
#pragma unroll
    for (int n = 0; n < 12; ++n) pv[n] = (f32x4){0.f, 0.f, 0.f, 0.f};
    float lacc[4] = {0.f, 0.f, 0.f, 0.f};

    const float scl = 0.088388347648318447f;  // 1/sqrt(128)

    for (int kt = 0; kt < Ss / 64; ++kt) {
        int t0 = kt * 64;
        // stage K tile [64][128] bf16, swizzled
#pragma unroll
        for (int i = 0; i < 4; ++i) {
            int ci = tid + i * 256;
            int row = ci >> 4, cb = ci & 15;
            short8 v = *(const short8*)&kbh[(size_t)(b * Ss + t0 + row) * DQK + cb * 8];
            *(short8*)((char*)Klds + ((row * 256 + cb * 16) ^ ((row & 7) << 4))) = v;
        }
        // stage V^T tile [192][64] bf16, swizzled
#pragma unroll
        for (int i = 0; i < 6; ++i) {
            int ci = tid + i * 256;
            int row = ci >> 3, cb = ci & 7;
            short8 v = *(const short8*)&vT[((size_t)(b * DV + row)) * Ss + t0 + cb * 8];
            *(short8*)((char*)VTlds + ((row * 128 + cb * 16) ^ ((row & 7) << 4))) = v;
        }
        __syncthreads();

        // QK^T: 16 MFMA -> s[n] = 16x16 tiles over 64 keys
        f32x4 s[4];
#pragma unroll
        for (int n = 0; n < 4; ++n) s[n] = (f32x4){0.f, 0.f, 0.f, 0.f};
#pragma unroll
        for (int c = 0; c < 4; ++c) {
#pragma unroll
            for (int n = 0; n < 4; ++n) {
                short8 kf = *(const short8*)((char*)Klds +
                            ((li * 256 + g * 16 + n * 4096 + c * 64) ^ mask));
                s[n] = __builtin_amdgcn_mfma_f32_16x16x32_bf16(qf[c], kf, s[n], 0, 0, 0);
            }
        }

        // P = exp(5*tanh(z/5)) (bounded logits -> fixed-shift softmax, no online max)
        float rs[4] = {0.f, 0.f, 0.f, 0.f};
#pragma unroll
        for (int n = 0; n < 4; ++n) {
#pragma unroll
            for (int r = 0; r < 4; ++r) {
                float z = s[n][r] * scl;
                float u = __expf(0.4f * z);
                float p = __expf(5.0f - 10.0f * __builtin_amdgcn_rcpf(u + 1.0f));
                rs[r] += p;
                int row = g * 4 + r;
                __hip_bfloat16 hb = __float2bfloat16(p);
                *(ushort*)((char*)Plds + w * 2048 +
                           ((row * 128 + n * 32 + li * 2) ^ ((row & 7) << 4))) =
                    *reinterpret_cast<ushort*>(&hb);
            }
        }
#pragma unroll
        for (int r = 0; r < 4; ++r) {
            float v = rs[r];
            v += __shfl_xor(v, 1); v += __shfl_xor(v, 2);
            v += __shfl_xor(v, 4); v += __shfl_xor(v, 8);
            lacc[r] += v;
        }

        // PV: 24 MFMA, A = P (from per-wave LDS), B = V^T tile
#pragma unroll
        for (int c2 = 0; c2 < 2; ++c2) {
            short8 pa = *(const short8*)((char*)Plds + w * 2048 +
                        ((li * 128 + c2 * 64 + g * 16) ^ mask));
#pragma unroll
            for (int n = 0; n < 12; ++n) {
                short8 vf = *(const short8*)((char*)VTlds +
                            ((n * 2048 + li * 128 + c2 * 64 + g * 16) ^ mask));
                pv[n] = __builtin_amdgcn_mfma_f32_16x16x32_bf16(pa, vf, pv[n], 0, 0, 0);
            }
        }
        __syncthreads();
    }

    // epilogue: divide by row sums, write fp32 y[b][s][gq][d]
    float invl[4];
#pragma unroll
    for (int r = 0; r < 4; ++r) invl[r] = 1.0f / lacc[r];
#pragma unroll
    for (int n = 0; n < 12; ++n) {
#pragma unroll
        for (int r = 0; r < 4; ++r) {
            int qr = q0 + w * 16 + g * 4 + r;
            ya[((size_t)(b * Ss + qr) * HQ + gq) * DV + n * 16 + li] = pv[n][r] * invl[r];
        }
    }
}

// ---------------- launch ----------------
extern "C" void kernel_launch(void* const* d_in, const int* in_sizes, int n_in,
                              void* d_out, int out_size, void* d_ws, size_t ws_size,
                              hipStream_t stream) {
    const float* x         = (const float*)d_in[0];
    const float* bn1_scale = (const float*)d_in[1];
    const float* q_w       = (const float*)d_in[2];
    const float* k_w       = (const float*)d_in[3];
    const float* v_w       = (const float*)d_in[4];
    const float* qn_w      = (const float*)d_in[5];
    const float* qn_b      = (const float*)d_in[6];
    const float* kn_w      = (const float*)d_in[7];
    const float* kn_b      = (const float*)d_in[8];
    const float* vn_w      = (const float*)d_in[9];
    const float* vn_b      = (const float*)d_in[10];
    const float* bn2_scale = (const float*)d_in[11];
    const float* out_w     = (const float*)d_in[12];
    const float* out_b     = (const float*)d_in[13];
    float* out = (float*)d_out;

    float* ws   = (float*)d_ws;
    float* ms1  = ws;                       // 1536
    float* ms2  = ws + 1536;                // 1536
    float* xb   = ws + 4096;                // 4096*1536 fp32 (phase A)
    float* qb   = xb + (size_t)ROWS * Cc;   // 4096*1024
    float* kb   = qb + (size_t)ROWS * HQ * DQK;  // 4096*128
    float* vb   = kb + (size_t)ROWS * DQK;       // 4096*192
    float* ya   = vb + (size_t)ROWS * DV;        // 4096*1536
    float* proj = xb;  // out-proj output reuses xb region (after attention)

    // bf16 buffers alias the xb region (xb fp32 is dead after the QKV GEMMs,
    // and proj overwrites only after attention has consumed these)
    ushort* qbh = (ushort*)xb;                                  // 4096*1024 bf16
    ushort* kbh = qbh + (size_t)ROWS * HQ * DQK;                // 4096*128
    ushort* vbh = kbh + (size_t)ROWS * DQK;                     // 4096*192
    ushort* vTb = vbh + (size_t)ROWS * DV;                      // 2*192*2048

    hipMemsetAsync(ms1, 0, 2 * Cc * sizeof(float), stream);

    // rms_bn1
    sq_reduce<<<dim3(Cc / 256, ROWS / 128), 256, 0, stream>>>(x, ms1, Cc);
    rms_apply<<<2048, 256, 0, stream>>>(x, ms1, bn1_scale, xb, Cc, (size_t)ROWS * Cc);

    // QKV projections (fp32)
    gemm_abT<<<dim3((HQ * DQK) / 64, ROWS / 64), 256, 0, stream>>>(
        xb, q_w, nullptr, qb, ROWS, HQ * DQK, Cc, 0);
    gemm_abT<<<dim3(DQK / 64, ROWS / 64), 256, 0, stream>>>(
        xb, k_w, nullptr, kb, ROWS, DQK, Cc, 0);
    gemm_abT<<<dim3(DV / 64, ROWS / 64), 256, 0, stream>>>(
        xb, v_w, nullptr, vb, ROWS, DV, Cc, 0);

    // LayerNorm + RoPE -> bf16
    ln_rope<DQK, 1><<<ROWS * HQ, DQK, 0, stream>>>(qb, qbh, qn_w, qn_b, HQ);
    ln_rope<DQK, 1><<<ROWS, DQK, 0, stream>>>(kb, kbh, kn_w, kn_b, 1);
    ln_rope<DV, 0><<<ROWS, DV, 0, stream>>>(vb, vbh, vn_w, vn_b, 1);

    // V transpose for PV B-fragments
    transpose_v<<<dim3(Ss / 64, DV / 64, Bb), 256, 0, stream>>>(vbh, vTb);

    // MFMA attention
    attn_mfma<<<dim3(Ss / 64, HQ, Bb), 256, 0, stream>>>(qbh, kbh, vTb, ya);

    // output projection + bias (fp32)
    gemm_abT<<<dim3(Cc / 64, ROWS / 64), 256, 0, stream>>>(
        ya, out_w, out_b, proj, ROWS, Cc, Cc, 1);

    // rms_bn2
    sq_reduce<<<dim3(Cc / 256, ROWS / 128), 256, 0, stream>>>(proj, ms2, Cc);
    rms_apply<<<2048, 256, 0, stream>>>(proj, ms2, bn2_scale, out, Cc, (size_t)ROWS * Cc);
}

// Round 12
// 370.292 us; speedup vs baseline: 21.0024x; 3.2703x over previous
//
#include <hip/hip_runtime.h>
#include <hip/hip_bf16.h>
#include <math.h>

#define Bb 2
#define Ss 2048
#define Cc 1536
#define HQ 8
#define DQK 128
#define DV 192
#define ROWS (Bb*Ss)          // 4096
#define NQKV 1408             // 1024 q + 128 k + 192 v + 64 pad (11*128)
#define EPSf 1e-5f
#define CLIPf 5.0f

typedef short short8 __attribute__((ext_vector_type(8)));
typedef float f32x4 __attribute__((ext_vector_type(4)));
typedef unsigned short ushort;
typedef ushort us4 __attribute__((ext_vector_type(4)));

// ---------------- helpers ----------------
__device__ __forceinline__ float wave_sum(float v) {
#pragma unroll
    for (int off = 32; off >= 1; off >>= 1) v += __shfl_xor(v, off);
    return v;
}

__device__ __forceinline__ ushort bf16_bits(float f) {
    __hip_bfloat16 hb = __float2bfloat16(f);
    return *reinterpret_cast<ushort*>(&hb);
}

__device__ __forceinline__ void gld16(const void* g, void* l) {
    __builtin_amdgcn_global_load_lds(
        (const __attribute__((address_space(1))) void*)g,
        (__attribute__((address_space(3))) void*)l, 16, 0, 0);
}

// ---------------- rms_bn reduce (per-channel over B*S) ----------------
__global__ void sq_reduce(const float* __restrict__ x, float* __restrict__ ms, int ncols) {
    int ch = blockIdx.x * blockDim.x + threadIdx.x;
    int r0 = blockIdx.y * 128;
    float acc = 0.f;
    for (int r = r0; r < r0 + 128; ++r) {
        float v = x[(size_t)r * ncols + ch];
        acc += v * v;
    }
    atomicAdd(&ms[ch], acc);
}

// ---------------- rms apply, vectorized x4; BF16 template selects output ----------------
template <int BF16>
__global__ void rms_apply_v(const float* __restrict__ x, const float* __restrict__ ms,
                            const float* __restrict__ scale, void* __restrict__ outp,
                            int ncols4, size_t total4) {
    for (size_t i = (size_t)blockIdx.x * blockDim.x + threadIdx.x; i < total4;
         i += (size_t)gridDim.x * blockDim.x) {
        int c4 = (int)(i % ncols4);
        float4 v = ((const float4*)x)[i];
        float4 m4 = ((const float4*)ms)[c4];
        float4 s4 = ((const float4*)scale)[c4];
        float o0 = v.x * rsqrtf(m4.x * (1.0f / ROWS) + EPSf) * s4.x;
        float o1 = v.y * rsqrtf(m4.y * (1.0f / ROWS) + EPSf) * s4.y;
        float o2 = v.z * rsqrtf(m4.z * (1.0f / ROWS) + EPSf) * s4.z;
        float o3 = v.w * rsqrtf(m4.w * (1.0f / ROWS) + EPSf) * s4.w;
        if (BF16) {
            us4 o = {bf16_bits(o0), bf16_bits(o1), bf16_bits(o2), bf16_bits(o3)};
            ((us4*)outp)[i] = o;
        } else {
            float4 o = {o0, o1, o2, o3};
            ((float4*)outp)[i] = o;
        }
    }
}

// ---------------- fp32 -> bf16 convert (x4) ----------------
__global__ void cvt_bf16(const float* __restrict__ in, ushort* __restrict__ out, int n4) {
    int i = blockIdx.x * blockDim.x + threadIdx.x;
    if (i >= n4) return;
    float4 v = ((const float4*)in)[i];
    us4 o = {bf16_bits(v.x), bf16_bits(v.y), bf16_bits(v.z), bf16_bits(v.w)};
    ((us4*)out)[i] = o;
}

// ---------------- bf16 MFMA GEMM: C[M,N]f32 = A[M,K] * W[N,K]^T (+bias) ----------------
// BM=BN=128, BK=32, 256 thr (2x2 waves, 64x64/wave, 4x4 frags of 16x16x32).
// LDS layout [g][row][8] (g = k-octet) => fragment ds_read_b128 is conflict-free;
// staging via global_load_lds with pre-permuted per-lane global source.
__global__ __launch_bounds__(256) void gemm_bf16(const ushort* __restrict__ A,
                                                 const ushort* __restrict__ W,
                                                 const float* __restrict__ bias,
                                                 float* __restrict__ Cout,
                                                 int N, int K, int hasBias) {
    __shared__ ushort AS[4096];  // 8 KB
    __shared__ ushort WS[4096];  // 8 KB
    int tid = threadIdx.x;
    int w = tid >> 6, lane = tid & 63;
    int gl = lane >> 4, li = lane & 15;
    int wr = w >> 1, wc = w & 1;
    int m0 = blockIdx.y * 128, n0 = blockIdx.x * 128;

    int r = tid & 127, gg = tid >> 7;  // staging: element-group eg=j*256+tid -> (g,row)
    const ushort* pA = A + (size_t)(m0 + r) * K + gg * 8;
    const ushort* pW = W + (size_t)(n0 + r) * K + gg * 8;
    ushort* lA0 = &AS[w * 512];
    ushort* lA1 = &AS[2048 + w * 512];
    ushort* lW0 = &WS[w * 512];
    ushort* lW1 = &WS[2048 + w * 512];

    const ushort* fA = &AS[(gl * 128 + wr * 64 + li) * 8];
    const ushort* fW = &WS[(gl * 128 + wc * 64 + li) * 8];

    f32x4 acc[4][4];
#pragma unroll
    for (int m = 0; m < 4; ++m)
#pragma unroll
        for (int n = 0; n < 4; ++n) acc[m][n] = (f32x4){0.f, 0.f, 0.f, 0.f};

    for (int kk = 0; kk < K; kk += 32) {
        __syncthreads();
        gld16(pA + kk, lA0);
        gld16(pA + kk + 16, lA1);
        gld16(pW + kk, lW0);
        gld16(pW + kk + 16, lW1);
        __syncthreads();
        short8 a[4], b[4];
#pragma unroll
        for (int m = 0; m < 4; ++m) a[m] = *(const short8*)(fA + m * 128);
#pragma unroll
        for (int n = 0; n < 4; ++n) b[n] = *(const short8*)(fW + n * 128);
#pragma unroll
        for (int m = 0; m < 4; ++m)
#pragma unroll
            for (int n = 0; n < 4; ++n)
                acc[m][n] = __builtin_amdgcn_mfma_f32_16x16x32_bf16(a[m], b[n], acc[m][n], 0, 0, 0);
    }

#pragma unroll
    for (int m = 0; m < 4; ++m) {
        int row = m0 + wr * 64 + m * 16 + gl * 4;
#pragma unroll
        for (int n = 0; n < 4; ++n) {
            int col = n0 + wc * 64 + n * 16 + li;
            float bv = hasBias ? bias[col] : 0.0f;
#pragma unroll
            for (int rr = 0; rr < 4; ++rr)
                Cout[(size_t)(row + rr) * N + col] = acc[m][n][rr] + bv;
        }
    }
}

// ---------------- LayerNorm (+RoPE), one wave per row, bf16 out ----------------
template <int D, int ROPE>
__global__ void ln_rope_w(const float* __restrict__ in, ushort* __restrict__ outb,
                          const float* __restrict__ w, const float* __restrict__ b,
                          int gdiv, int rstride, int coff, int nrows) {
    int wid = blockIdx.x * (blockDim.x >> 6) + (threadIdx.x >> 6);
    if (wid >= nrows) return;
    int lane = threadIdx.x & 63;
    const float* src = in + (size_t)(wid / gdiv) * rstride + (size_t)(wid % gdiv) * D + coff;

    if (D == 128) {
        float2 e = *(const float2*)&src[2 * lane];
        float mu = wave_sum(e.x + e.y) * (1.0f / D);
        float d0 = e.x - mu, d1 = e.y - mu;
        float var = wave_sum(d0 * d0 + d1 * d1) * (1.0f / D);
        float rs = rsqrtf(var + EPSf);
        float n0 = d0 * rs * w[2 * lane] + b[2 * lane];
        float n1 = d1 * rs * w[2 * lane + 1] + b[2 * lane + 1];
        float r0 = n0, r1 = n1;
        if (ROPE) {
            int s = (wid / gdiv) % Ss;
            float geom = expf((float)lane * (logf(8129.0f) / 63.0f));
            float invf = 1.0f / ((float)lane + geom);
            float th = (float)s * invf;
            float ct = cosf(th), st = sinf(th);
            r0 = n0 * ct - n1 * st;
            r1 = n1 * ct + n0 * st;
        }
        ushort2 o = {bf16_bits(r0), bf16_bits(r1)};
        *(ushort2*)&outb[(size_t)wid * D + 2 * lane] = o;
    } else {  // D == 192, no rope
        float e0 = src[lane], e1 = src[lane + 64], e2 = src[lane + 128];
        float mu = wave_sum(e0 + e1 + e2) * (1.0f / D);
        float d0 = e0 - mu, d1 = e1 - mu, d2 = e2 - mu;
        float var = wave_sum(d0 * d0 + d1 * d1 + d2 * d2) * (1.0f / D);
        float rs = rsqrtf(var + EPSf);
        outb[(size_t)wid * D + lane]       = bf16_bits(d0 * rs * w[lane] + b[lane]);
        outb[(size_t)wid * D + lane + 64]  = bf16_bits(d1 * rs * w[lane + 64] + b[lane + 64]);
        outb[(size_t)wid * D + lane + 128] = bf16_bits(d2 * rs * w[lane + 128] + b[lane + 128]);
    }
}

// ---------------- V transpose: vbh[b][t][d] -> vT[b][d][t] (bf16) ----------------
__global__ __launch_bounds__(256) void transpose_v(const ushort* __restrict__ vbh,
                                                   ushort* __restrict__ vT) {
    __shared__ ushort tb[64][72];
    int t0 = blockIdx.x * 64, d0 = blockIdx.y * 64, b = blockIdx.z;
    int tid = threadIdx.x;
#pragma unroll
    for (int i = 0; i < 2; ++i) {
        int ci = tid + i * 256;
        int t = ci >> 3, dc = ci & 7;
        short8 v = *(const short8*)&vbh[((size_t)(b * Ss + t0 + t)) * DV + d0 + dc * 8];
        *(short8*)&tb[t][dc * 8] = v;
    }
    __syncthreads();
#pragma unroll
    for (int i = 0; i < 2; ++i) {
        int ci = tid + i * 256;
        int d = ci >> 3, tc = ci & 7;
        short8 v;
#pragma unroll
        for (int j = 0; j < 8; ++j) v[j] = (short)tb[tc * 8 + j][d];
        *(short8*)&vT[((size_t)(b * DV + d0 + d)) * Ss + t0 + tc * 8] = v;
    }
}

// ---------------- MFMA flash attention (bf16 out) ----------------
__global__ __launch_bounds__(256, 2) void attn_mfma(const ushort* __restrict__ qbh,
                                                    const ushort* __restrict__ kbh,
                                                    const ushort* __restrict__ vT,
                                                    ushort* __restrict__ yab) {
    __shared__ ushort Klds[64 * 128];
    __shared__ ushort VTlds[192 * 64];
    __shared__ ushort Plds[4 * 16 * 64];
    int tid = threadIdx.x;
    int b = blockIdx.z, gq = blockIdx.y;
    int q0 = blockIdx.x * 64;
    int w = tid >> 6, lane = tid & 63;
    int g = lane >> 4, li = lane & 15;
    int mask = (li & 7) << 4;

    short8 qf[4];
    {
        int qrow = q0 + w * 16 + li;
        const ushort* qptr = qbh + ((size_t)(b * Ss + qrow) * HQ + gq) * DQK + g * 8;
#pragma unroll
        for (int c = 0; c < 4; ++c) qf[c] = *(const short8*)(qptr + c * 32);
    }

    f32x4 pv[12];
#pragma unroll
    for (int n = 0; n < 12; ++n) pv[n] = (f32x4){0.f, 0.f, 0.f, 0.f};
    float lacc[4] = {0.f, 0.f, 0.f, 0.f};

    const float scl = 0.088388347648318447f;

    for (int kt = 0; kt < Ss / 64; ++kt) {
        int t0 = kt * 64;
#pragma unroll
        for (int i = 0; i < 4; ++i) {
            int ci = tid + i * 256;
            int row = ci >> 4, cb = ci & 15;
            short8 v = *(const short8*)&kbh[(size_t)(b * Ss + t0 + row) * DQK + cb * 8];
            *(short8*)((char*)Klds + ((row * 256 + cb * 16) ^ ((row & 7) << 4))) = v;
        }
#pragma unroll
        for (int i = 0; i < 6; ++i) {
            int ci = tid + i * 256;
            int row = ci >> 3, cb = ci & 7;
            short8 v = *(const short8*)&vT[((size_t)(b * DV + row)) * Ss + t0 + cb * 8];
            *(short8*)((char*)VTlds + ((row * 128 + cb * 16) ^ ((row & 7) << 4))) = v;
        }
        __syncthreads();

        f32x4 s[4];
#pragma unroll
        for (int n = 0; n < 4; ++n) s[n] = (f32x4){0.f, 0.f, 0.f, 0.f};
#pragma unroll
        for (int c = 0; c < 4; ++c) {
#pragma unroll
            for (int n = 0; n < 4; ++n) {
                short8 kf = *(const short8*)((char*)Klds +
                            ((li * 256 + g * 16 + n * 4096 + c * 64) ^ mask));
                s[n] = __builtin_amdgcn_mfma_f32_16x16x32_bf16(qf[c], kf, s[n], 0, 0, 0);
            }
        }

        float rsum[4] = {0.f, 0.f, 0.f, 0.f};
#pragma unroll
        for (int n = 0; n < 4; ++n) {
#pragma unroll
            for (int rr = 0; rr < 4; ++rr) {
                float z = s[n][rr] * scl;
                float u = __expf(0.4f * z);
                float p = __expf(5.0f - 10.0f * __builtin_amdgcn_rcpf(u + 1.0f));
                rsum[rr] += p;
                int row = g * 4 + rr;
                *(ushort*)((char*)Plds + w * 2048 +
                           ((row * 128 + n * 32 + li * 2) ^ ((row & 7) << 4))) = bf16_bits(p);
            }
        }
#pragma unroll
        for (int rr = 0; rr < 4; ++rr) {
            float v = rsum[rr];
            v += __shfl_xor(v, 1); v += __shfl_xor(v, 2);
            v += __shfl_xor(v, 4); v += __shfl_xor(v, 8);
            lacc[rr] += v;
        }

#pragma unroll
        for (int c2 = 0; c2 < 2; ++c2) {
            short8 pa = *(const short8*)((char*)Plds + w * 2048 +
                        ((li * 128 + c2 * 64 + g * 16) ^ mask));
#pragma unroll
            for (int n = 0; n < 12; ++n) {
                short8 vf = *(const short8*)((char*)VTlds +
                            ((n * 2048 + li * 128 + c2 * 64 + g * 16) ^ mask));
                pv[n] = __builtin_amdgcn_mfma_f32_16x16x32_bf16(pa, vf, pv[n], 0, 0, 0);
            }
        }
        __syncthreads();
    }

    float invl[4];
#pragma unroll
    for (int rr = 0; rr < 4; ++rr) invl[rr] = 1.0f / lacc[rr];
#pragma unroll
    for (int n = 0; n < 12; ++n) {
#pragma unroll
        for (int rr = 0; rr < 4; ++rr) {
            int qr = q0 + w * 16 + g * 4 + rr;
            yab[((size_t)(b * Ss + qr) * HQ + gq) * DV + n * 16 + li] =
                bf16_bits(pv[n][rr] * invl[rr]);
        }
    }
}

// ---------------- launch ----------------
extern "C" void kernel_launch(void* const* d_in, const int* in_sizes, int n_in,
                              void* d_out, int out_size, void* d_ws, size_t ws_size,
                              hipStream_t stream) {
    const float* x         = (const float*)d_in[0];
    const float* bn1_scale = (const float*)d_in[1];
    const float* q_w       = (const float*)d_in[2];
    const float* k_w       = (const float*)d_in[3];
    const float* v_w       = (const float*)d_in[4];
    const float* qn_w      = (const float*)d_in[5];
    const float* qn_b      = (const float*)d_in[6];
    const float* kn_w      = (const float*)d_in[7];
    const float* kn_b      = (const float*)d_in[8];
    const float* vn_w      = (const float*)d_in[9];
    const float* vn_b      = (const float*)d_in[10];
    const float* bn2_scale = (const float*)d_in[11];
    const float* out_w     = (const float*)d_in[12];
    const float* out_b     = (const float*)d_in[13];
    float* out = (float*)d_out;

    char* wsb = (char*)d_ws;
    float* ms1 = (float*)wsb;                  // 1536 f32
    float* ms2 = ms1 + Cc;                     // 1536 f32
    char* base = wsb + 16384;
    ushort* xbh   = (ushort*)base;                              // 4096*1536 bf16
    ushort* qkvwh = xbh + (size_t)ROWS * Cc;                    // 1408*1536 bf16
    float*  qkvb  = (float*)(qkvwh + (size_t)NQKV * Cc);        // 4096*1408 f32
    ushort* owh   = (ushort*)(qkvb + (size_t)ROWS * NQKV);      // 1536*1536 bf16
    ushort* qbh   = owh + (size_t)Cc * Cc;                      // 4096*1024 bf16
    ushort* kbh   = qbh + (size_t)ROWS * HQ * DQK;              // 4096*128
    ushort* vbh   = kbh + (size_t)ROWS * DQK;                   // 4096*192
    ushort* vTb   = vbh + (size_t)ROWS * DV;                    // 2*192*2048
    ushort* yab   = vTb + (size_t)Bb * DV * Ss;                 // 4096*1536 bf16
    float*  proj  = (float*)base;  // aliases xbh/qkvwh/qkvb (dead by then)

    hipMemsetAsync(ms1, 0, 2 * Cc * sizeof(float), stream);

    // rms_bn1 -> bf16 activations
    sq_reduce<<<dim3(Cc / 256, ROWS / 128), 256, 0, stream>>>(x, ms1, Cc);
    rms_apply_v<1><<<2048, 256, 0, stream>>>(x, ms1, bn1_scale, xbh, Cc / 4,
                                             (size_t)ROWS * Cc / 4);

    // weights -> bf16 (q|k|v packed into one [1408][1536]; rows 1344..1407 garbage, unread)
    cvt_bf16<<<(HQ * DQK * Cc / 4 + 255) / 256, 256, 0, stream>>>(q_w, qkvwh, HQ * DQK * Cc / 4);
    cvt_bf16<<<(DQK * Cc / 4 + 255) / 256, 256, 0, stream>>>(k_w, qkvwh + (size_t)1024 * Cc, DQK * Cc / 4);
    cvt_bf16<<<(DV * Cc / 4 + 255) / 256, 256, 0, stream>>>(v_w, qkvwh + (size_t)1152 * Cc, DV * Cc / 4);
    cvt_bf16<<<(Cc * Cc / 4 + 255) / 256, 256, 0, stream>>>(out_w, owh, Cc * Cc / 4);

    // fused QKV projection (bf16 MFMA)
    gemm_bf16<<<dim3(NQKV / 128, ROWS / 128), 256, 0, stream>>>(
        xbh, qkvwh, nullptr, qkvb, NQKV, Cc, 0);

    // LayerNorm + RoPE -> bf16
    ln_rope_w<DQK, 1><<<ROWS * HQ / 4, 256, 0, stream>>>(qkvb, qbh, qn_w, qn_b, HQ, NQKV, 0, ROWS * HQ);
    ln_rope_w<DQK, 1><<<ROWS / 4, 256, 0, stream>>>(qkvb, kbh, kn_w, kn_b, 1, NQKV, 1024, ROWS);
    ln_rope_w<DV, 0><<<ROWS / 4, 256, 0, stream>>>(qkvb, vbh, vn_w, vn_b, 1, NQKV, 1152, ROWS);

    // V transpose
    transpose_v<<<dim3(Ss / 64, DV / 64, Bb), 256, 0, stream>>>(vbh, vTb);

    // attention -> bf16 y
    attn_mfma<<<dim3(Ss / 64, HQ, Bb), 256, 0, stream>>>(qbh, kbh, vTb, yab);

    // output projection + bias (bf16 MFMA -> f32)
    gemm_bf16<<<dim3(Cc / 128, ROWS / 128), 256, 0, stream>>>(
        yab, owh, out_b, proj, Cc, Cc, 1);

    // rms_bn2 -> f32 out
    sq_reduce<<<dim3(Cc / 256, ROWS / 128), 256, 0, stream>>>(proj, ms2, Cc);
    rms_apply_v<0><<<2048, 256, 0, stream>>>(proj, ms2, bn2_scale, out, Cc / 4,
                                             (size_t)ROWS * Cc / 4);
}